// Round 9
// baseline (109.238 us; speedup 1.0000x reference)
//
#include <hip/hip_runtime.h>

#define N_ROWS 8192
#define DIM    128
#define BM     128
#define NBLK   (N_ROWS / BM)           // 64
#define NTRI   (NBLK * (NBLK + 1) / 2) // 2080

// Fragment-major blob: per 128-row panel (64KB):
//   phase p (K=32 chunk, 16KB) -> g32 group (32 rows, 4KB) ->
//   frag f = {q0_hi, q1_hi, q0_lo, q1_lo} (1KB each) -> slot l*16B where
//   slot l = (row&31) + ksub_parity*32, data = 8 fp16 of k = p*32+ksub*8..+8
// A wave's MFMA fragment read is base + lane*16  (sequential, conflict-free);
// global_load_lds fill is linear; prep writes are 16B-granular coalesced-ish.
#define BLOB_PER_RB   65536
#define BLOB_PER_PH   16384

typedef _Float16 half8 __attribute__((ext_vector_type(8)));
typedef float    f32x16 __attribute__((ext_vector_type(16)));

typedef const __attribute__((address_space(1))) unsigned int glb_uint;
typedef __attribute__((address_space(3))) unsigned int lds_uint;

__device__ inline void gload_lds16(const void* g, void* l)
{
    __builtin_amdgcn_global_load_lds((glb_uint*)(uintptr_t)g,
                                     (lds_uint*)(uintptr_t)l, 16, 0, 0);
}

// ---------------------------------------------------------------------------
// Prep: X fp32 -> fragment-major fp16-split blob + row norms.
// t = row*16 + p*4 + ksub; thread loads 8 floats, writes hi 16B + lo 16B.
__global__ __launch_bounds__(256)
void prep_tiled(const float* __restrict__ X, char* __restrict__ blob,
                float* __restrict__ norms)
{
    const int t    = blockIdx.x * 256 + threadIdx.x;  // 0 .. 131071
    const int ksub = t & 3;
    const int p    = (t >> 2) & 3;
    const int row  = t >> 4;

    const float4* src = (const float4*)(X + (size_t)row * DIM + p * 32 + ksub * 8);
    const float4 v0 = src[0], v1 = src[1];
    const float xs[8] = {v0.x, v0.y, v0.z, v0.w, v1.x, v1.y, v1.z, v1.w};

    half8 h, l;
    float ns = 0.0f;
    #pragma unroll
    for (int i = 0; i < 8; ++i) {
        const float x = xs[i];
        const _Float16 hh = (_Float16)x;
        h[i] = hh;
        l[i] = (_Float16)(x - (float)hh);
        ns = fmaf(x, x, ns);
    }

    const int rb   = row >> 7;
    const int r    = row & 127;
    const int g32  = r >> 5;
    const int q    = ksub >> 1;
    const int slot = (r & 31) + (ksub & 1) * 32;
    char* base = blob + (size_t)rb * BLOB_PER_RB + p * BLOB_PER_PH
               + g32 * 4096 + q * 1024 + slot * 16;
    *(half8*)(base)        = h;   // hi frag
    *(half8*)(base + 2048) = l;   // lo frag (f offset 2 -> +2KB)

    // 16 consecutive threads cover one row (4 phases x 4 ksub)
    #pragma unroll
    for (int off = 1; off <= 8; off <<= 1) ns += __shfl_xor(ns, off);
    if ((t & 15) == 0) norms[row] = ns;
}

// ---------------------------------------------------------------------------
// Main: one block per upper-triangle 128x128 tile. Fragment-major LDS
// (conflict-free lane-sequential reads), single-buffer 2-barrier loop,
// 4 blocks/CU for TLP, split-fp16 3-term MFMA, distance epilogue.
__global__ __launch_bounds__(256, 4)
void pairsum_mfma(const char* __restrict__ blob, const float* __restrict__ norms,
                  const int* __restrict__ Y, double* __restrict__ gsum)
{
    // triangular decode: cum(b) = b*(129-b)/2
    const int kb = blockIdx.x;
    int bi = (int)((129.0f - sqrtf(fmaf(-8.0f, (float)kb, 129.0f * 129.0f))) * 0.5f);
    while ((bi + 1) * (129 - (bi + 1)) / 2 <= kb) ++bi;
    while (bi * (129 - bi) / 2 > kb) --bi;
    const int bj = bi + (kb - bi * (129 - bi) / 2);
    const int i0 = bi * BM, j0 = bj * BM;

    const int tid  = threadIdx.x;
    const int lane = tid & 63;
    const int w    = tid >> 6;        // wave 0..3
    const int wy   = w >> 1;          // 2x2 wave grid, 64x64 each
    const int wx   = w & 1;
    const int lr   = lane & 31;
    const int lh   = lane >> 5;

    // LDS: A frag chunk 16KB + B frag chunk 16KB (single buffer)
    __shared__ __align__(16) char tile[32768];
    __shared__ float nI[BM], nJ[BM];
    __shared__ int   yI[BM], yJ[BM];
    __shared__ double wsum[4];

    if (tid < BM) { nI[tid] = norms[i0 + tid]; yI[tid] = Y[i0 + tid]; }
    else { const int r = tid & (BM - 1); nJ[r] = norms[j0 + r]; yJ[r] = Y[j0 + r]; }
    __syncthreads();

    const char* Apan = blob + (size_t)bi * BLOB_PER_RB;
    const char* Bpan = blob + (size_t)bj * BLOB_PER_RB;

    f32x16 acc[2][2];
    #pragma unroll
    for (int m = 0; m < 2; ++m)
        #pragma unroll
        for (int n = 0; n < 2; ++n)
            #pragma unroll
            for (int r = 0; r < 16; ++r)
                acc[m][n][r] = 0.0f;

    for (int p = 0; p < 4; ++p) {
        // stage phase p: A 16KB -> tile[0..16K), B 16KB -> tile[16K..32K)
        #pragma unroll
        for (int r = 0; r < 4; ++r) {
            gload_lds16(Apan + p * BLOB_PER_PH + r * 4096 + tid * 16,
                        tile + r * 4096 + tid * 16);
            gload_lds16(Bpan + p * BLOB_PER_PH + r * 4096 + tid * 16,
                        tile + 16384 + r * 4096 + tid * 16);
        }
        asm volatile("s_waitcnt vmcnt(0)" ::: "memory");
        __builtin_amdgcn_s_barrier();

        #pragma unroll
        for (int q = 0; q < 2; ++q) {
            half8 ah[2], al[2], bh[2], bl[2];
            #pragma unroll
            for (int m = 0; m < 2; ++m) {
                const int ga = (wy * 2 + m) * 4096 + q * 1024 + lane * 16;
                ah[m] = *(const half8*)(tile + ga);
                al[m] = *(const half8*)(tile + ga + 2048);
                const int gb = 16384 + (wx * 2 + m) * 4096 + q * 1024 + lane * 16;
                bh[m] = *(const half8*)(tile + gb);
                bl[m] = *(const half8*)(tile + gb + 2048);
            }
            #pragma unroll
            for (int m = 0; m < 2; ++m)
                #pragma unroll
                for (int n = 0; n < 2; ++n) {
                    acc[m][n] = __builtin_amdgcn_mfma_f32_32x32x16_f16(ah[m], bh[n], acc[m][n], 0, 0, 0);
                    acc[m][n] = __builtin_amdgcn_mfma_f32_32x32x16_f16(ah[m], bl[n], acc[m][n], 0, 0, 0);
                    acc[m][n] = __builtin_amdgcn_mfma_f32_32x32x16_f16(al[m], bh[n], acc[m][n], 0, 0, 0);
                }
        }
        __builtin_amdgcn_s_barrier();   // all waves done reading before refill
    }

    // epilogue: C/D map col=lane&31, row=(reg&3)+8*(reg>>2)+4*(lane>>5)
    float s = 0.0f;
    float nJv[2]; int yJv[2];
    #pragma unroll
    for (int n = 0; n < 2; ++n) {
        const int lj = wx * 64 + n * 32 + lr;
        nJv[n] = nJ[lj]; yJv[n] = yJ[lj];
    }
    #pragma unroll
    for (int m = 0; m < 2; ++m) {
        #pragma unroll
        for (int r = 0; r < 16; ++r) {
            const int rowin = (r & 3) + 8 * (r >> 2) + 4 * lh;
            const int li = wy * 64 + m * 32 + rowin;
            const float ni = nI[li];
            const int   yi = yI[li];
            const int   gi = i0 + li;
            #pragma unroll
            for (int n = 0; n < 2; ++n) {
                const int gj = j0 + wx * 64 + n * 32 + lr;
                float sq = fmaf(-2.0f, acc[m][n][r], ni + nJv[n]);
                sq = fmaxf(sq, 0.0f);
                const float d = __builtin_amdgcn_sqrtf(sq);
                if (gi < gj) s = fmaf((yi == yJv[n]) ? 1.0f : -0.5f, d, s);
            }
        }
    }

    #pragma unroll
    for (int off = 32; off > 0; off >>= 1) s += __shfl_down(s, off);
    if (lane == 0) wsum[w] = (double)s;
    __syncthreads();
    if (tid == 0) atomicAdd(gsum, wsum[0] + wsum[1] + wsum[2] + wsum[3]);
}

__global__ void finalize_kernel(const double* __restrict__ gsum, float* __restrict__ out)
{
    out[0] = (float)(2.0 * gsum[0]);
}

// ---------------------------------------------------------------------------
// Fallback (ws too small): round-1 VALU kernel, known-correct.
#define LDSPAD 4
#define LDB (BM + LDSPAD)
__global__ __launch_bounds__(256)
void pairsum_valu(const float* __restrict__ X, const int* __restrict__ Y,
                  double* __restrict__ gsum)
{
    const int bj = blockIdx.x, bi = blockIdx.y;
    if (bi > bj) return;
    const int tid = threadIdx.x;
    const int i0 = bi * BM, j0 = bj * BM;
    __shared__ float As[32][LDB], Bs[32][LDB];
    __shared__ float nI[BM], nJ[BM];
    __shared__ int yI[BM], yJ[BM];
    __shared__ double wsum[4];
    {
        const int r = tid & (BM - 1);
        const bool isJ = tid >= BM;
        const int row = (isJ ? j0 : i0) + r;
        const float4* p = (const float4*)(X + (size_t)row * DIM);
        float s = 0.f;
        #pragma unroll
        for (int q = 0; q < DIM / 4; ++q) {
            float4 v = p[q];
            s = fmaf(v.x, v.x, s); s = fmaf(v.y, v.y, s);
            s = fmaf(v.z, v.z, s); s = fmaf(v.w, v.w, s);
        }
        if (isJ) { nJ[r] = s; yJ[r] = Y[row]; }
        else     { nI[r] = s; yI[r] = Y[row]; }
    }
    float dot[8][8];
    #pragma unroll
    for (int m = 0; m < 8; ++m)
        #pragma unroll
        for (int n = 0; n < 8; ++n) dot[m][n] = 0.f;
    const int tx = tid & 15, ty = tid >> 4;
    for (int kc = 0; kc < DIM; kc += 32) {
        __syncthreads();
        #pragma unroll
        for (int p = 0; p < 4; ++p) {
            const int s2 = p * 256 + tid;
            const int row = s2 >> 3, kg = s2 & 7;
            const float4 va = *(const float4*)(X + (size_t)(i0 + row) * DIM + kc + kg * 4);
            const float4 vb = *(const float4*)(X + (size_t)(j0 + row) * DIM + kc + kg * 4);
            As[kg*4+0][row] = va.x; As[kg*4+1][row] = va.y;
            As[kg*4+2][row] = va.z; As[kg*4+3][row] = va.w;
            Bs[kg*4+0][row] = vb.x; Bs[kg*4+1][row] = vb.y;
            Bs[kg*4+2][row] = vb.z; Bs[kg*4+3][row] = vb.w;
        }
        __syncthreads();
        #pragma unroll
        for (int k = 0; k < 32; ++k) {
            float a[8], b[8];
            *(float4*)&a[0] = *(const float4*)&As[k][ty*8];
            *(float4*)&a[4] = *(const float4*)&As[k][ty*8+4];
            *(float4*)&b[0] = *(const float4*)&Bs[k][tx*8];
            *(float4*)&b[4] = *(const float4*)&Bs[k][tx*8+4];
            #pragma unroll
            for (int m = 0; m < 8; ++m)
                #pragma unroll
                for (int n = 0; n < 8; ++n)
                    dot[m][n] = fmaf(a[m], b[n], dot[m][n]);
        }
    }
    float s = 0.f;
    const int ib = ty * 8, jb = tx * 8;
    #pragma unroll
    for (int m = 0; m < 8; ++m) {
        const int gi = i0 + ib + m;
        const float ni = nI[ib + m];
        const int yi = yI[ib + m];
        #pragma unroll
        for (int n = 0; n < 8; ++n) {
            const int gj = j0 + jb + n;
            float sq = fmaf(-2.f, dot[m][n], ni + nJ[jb + n]);
            sq = fmaxf(sq, 0.f);
            const float d = __builtin_amdgcn_sqrtf(sq);
            if (gi < gj) s = fmaf((yi == yJ[jb + n]) ? 1.0f : -0.5f, d, s);
        }
    }
    #pragma unroll
    for (int off = 32; off > 0; off >>= 1) s += __shfl_down(s, off);
    const int lane = tid & 63, wid = tid >> 6;
    if (lane == 0) wsum[wid] = (double)s;
    __syncthreads();
    if (tid == 0) atomicAdd(gsum, wsum[0] + wsum[1] + wsum[2] + wsum[3]);
}

// ---------------------------------------------------------------------------
extern "C" void kernel_launch(void* const* d_in, const int* in_sizes, int n_in,
                              void* d_out, int out_size, void* d_ws, size_t ws_size,
                              hipStream_t stream)
{
    const float* X = (const float*)d_in[0];
    const int*   Y = (const int*)d_in[1];
    float* out = (float*)d_out;

    // ws layout: [0] double gsum | 64: blob 4MB | +4MB: norms 32KB
    const size_t OFF_BLOB = 64;
    const size_t OFF_NORM = OFF_BLOB + (size_t)NBLK * BLOB_PER_RB;
    const size_t REQ      = OFF_NORM + (size_t)N_ROWS * 4;

    double* gsum = (double*)d_ws;
    hipMemsetAsync(d_ws, 0, sizeof(double), stream);

    if (ws_size >= REQ) {
        char*  blob  = (char*)d_ws + OFF_BLOB;
        float* norms = (float*)((char*)d_ws + OFF_NORM);
        prep_tiled<<<(N_ROWS * 16) / 256, 256, 0, stream>>>(X, blob, norms);
        pairsum_mfma<<<NTRI, 256, 0, stream>>>(blob, norms, Y, gsum);
    } else {
        dim3 grid(NBLK, NBLK);
        pairsum_valu<<<grid, 256, 0, stream>>>(X, Y, gsum);
    }
    finalize_kernel<<<1, 1, 0, stream>>>(gsum, out);
}